// Round 1
// baseline (438.640 us; speedup 1.0000x reference)
//
#include <hip/hip_runtime.h>

#define K_IN 256
#define O_OUT 64

// ---------------- W transpose: Wt[k][o] = W[o][k] ----------------
__global__ __launch_bounds__(256) void k_transpose_w(const float* __restrict__ W,
                                                     float* __restrict__ Wt) {
  int i = blockIdx.x * 256 + threadIdx.x;  // 64*256 = 16384 launched exactly
  int o = i >> 8;
  int k = i & 255;
  Wt[k * O_OUT + o] = W[i];
}

// ---------------- GEMM + bias + ReLU -----------------------------
// Block: 256 threads = 4 waves. Wave w computes out-feats [16w,16w+16) for
// 64 nodes (lane = node). W is read via wave-uniform scalar loads (SGPR
// broadcast); x staged transposed through LDS (pad 65 -> conflict-free).
__global__ __launch_bounds__(256) void k_gemm_relu(const float* __restrict__ x,
                                                   const float* __restrict__ Wt,
                                                   const float* __restrict__ b,
                                                   float* __restrict__ h, int N) {
  __shared__ float xs[64][65];
  const int tid = threadIdx.x;
  const int lane = tid & 63;
  const int o0 = __builtin_amdgcn_readfirstlane((tid >> 6) * 16);
  const int n0 = blockIdx.x * 64;

  float acc[16];
#pragma unroll
  for (int j = 0; j < 16; ++j) acc[j] = 0.f;

  for (int kc = 0; kc < K_IN; kc += 64) {
    __syncthreads();
    // stage x[n0..n0+63][kc..kc+63] transposed: xs[k][n]
#pragma unroll
    for (int p = 0; p < 4; ++p) {
      int r = p * 16 + (tid >> 4);   // local node 0..63
      int kq = (tid & 15) * 4;       // k offset 0..60
      int row = n0 + r;
      float4 v = make_float4(0.f, 0.f, 0.f, 0.f);
      if (row < N) v = *(const float4*)(x + (size_t)row * K_IN + kc + kq);
      xs[kq + 0][r] = v.x;
      xs[kq + 1][r] = v.y;
      xs[kq + 2][r] = v.z;
      xs[kq + 3][r] = v.w;
    }
    __syncthreads();
#pragma unroll 8
    for (int k = 0; k < 64; ++k) {
      float xv = xs[k][lane];
      const float* w = Wt + (kc + k) * O_OUT + o0;  // wave-uniform -> s_load
#pragma unroll
      for (int j = 0; j < 16; ++j) acc[j] = fmaf(xv, w[j], acc[j]);
    }
  }

  int node = n0 + lane;
  if (node < N) {
#pragma unroll
    for (int j = 0; j < 16; ++j) {
      float v = acc[j] + b[o0 + j];
      h[(size_t)node * O_OUT + o0 + j] = fmaxf(v, 0.f);
    }
  }
}

// ---------------- degree histogram -------------------------------
__global__ __launch_bounds__(256) void k_hist(const int* __restrict__ dst,
                                              int* __restrict__ counts, int E) {
  int i = blockIdx.x * 256 + threadIdx.x;
  if (i < E) atomicAdd(&counts[dst[i]], 1);
}

// ---------------- single-block exclusive scan --------------------
__global__ __launch_bounds__(1024) void k_scan(const int* __restrict__ counts,
                                               int* __restrict__ offsets, int n) {
  __shared__ int lds[1024];
  const int t = threadIdx.x;
  const int C = (n + 1023) / 1024;
  int lo = t * C;
  int hi = lo + C;
  if (hi > n) hi = n;
  int s = 0;
  for (int i = lo; i < hi; ++i) s += counts[i];
  lds[t] = s;
  __syncthreads();
  for (int off = 1; off < 1024; off <<= 1) {
    int v = 0;
    if (t >= off) v = lds[t - off];
    __syncthreads();
    lds[t] += v;
    __syncthreads();
  }
  int run = lds[t] - s;  // exclusive prefix for this thread's chunk
  for (int i = lo; i < hi; ++i) {
    offsets[i] = run;
    run += counts[i];
  }
  if (t == 1023) offsets[n] = lds[1023];
}

// ---------------- scatter edges into CSR buckets -----------------
__global__ __launch_bounds__(256) void k_scatter(const int* __restrict__ src,
                                                 const int* __restrict__ dst,
                                                 int* __restrict__ cursor,
                                                 int* __restrict__ bucket, int E) {
  int i = blockIdx.x * 256 + threadIdx.x;
  if (i < E) {
    int d = dst[i];
    int pos = atomicAdd(&cursor[d], 1);
    bucket[pos] = src[i];
  }
}

// ---------------- per-node mean aggregation ----------------------
// One wave per dst node; lane = feature. bucket[i] is wave-uniform -> s_load;
// h-row reads are 256 B coalesced (L2/LLC-resident).
__global__ __launch_bounds__(256) void k_agg(const int* __restrict__ offsets,
                                             const int* __restrict__ bucket,
                                             const float* __restrict__ h,
                                             float* __restrict__ out, int N) {
  int node = blockIdx.x * 4 + (threadIdx.x >> 6);
  if (node >= N) return;
  node = __builtin_amdgcn_readfirstlane(node);
  const int lane = threadIdx.x & 63;
  const int start = __builtin_amdgcn_readfirstlane(offsets[node]);
  const int end = __builtin_amdgcn_readfirstlane(offsets[node + 1]);

  float acc = 0.f;
  int i = start;
  for (; i + 4 <= end; i += 4) {
    int s0 = bucket[i + 0];
    int s1 = bucket[i + 1];
    int s2 = bucket[i + 2];
    int s3 = bucket[i + 3];
    acc += h[(size_t)s0 * O_OUT + lane];
    acc += h[(size_t)s1 * O_OUT + lane];
    acc += h[(size_t)s2 * O_OUT + lane];
    acc += h[(size_t)s3 * O_OUT + lane];
  }
  for (; i < end; ++i) acc += h[(size_t)bucket[i] * O_OUT + lane];

  float deg = (float)(end - start);
  out[(size_t)node * O_OUT + lane] = acc / fmaxf(deg, 1.f);
}

// ---------------- launch -----------------------------------------
extern "C" void kernel_launch(void* const* d_in, const int* in_sizes, int n_in,
                              void* d_out, int out_size, void* d_ws, size_t ws_size,
                              hipStream_t stream) {
  const float* x = (const float*)d_in[0];
  const float* W = (const float*)d_in[1];
  const float* b = (const float*)d_in[2];
  const int* esrc = (const int*)d_in[3];
  const int* edst = (const int*)d_in[4];
  float* out = (float*)d_out;

  const int N = in_sizes[0] / K_IN;  // 50000
  const int E = in_sizes[3];         // 1600000

  // workspace layout (bytes)
  char* ws = (char*)d_ws;
  float* Wt = (float*)ws;                                  // 65,536 B
  float* h = (float*)(ws + 65536);                         // N*64*4 = 12,800,000 B
  size_t off = 65536 + (size_t)N * O_OUT * sizeof(float);
  int* counts = (int*)(ws + off);                          // N ints
  off += (size_t)N * sizeof(int);
  int* offsets = (int*)(ws + off);                         // N+1 ints
  off += ((size_t)N + 4) * sizeof(int);
  int* cursor = (int*)(ws + off);                          // N ints
  off += (size_t)N * sizeof(int);
  int* bucket = (int*)(ws + off);                          // E ints

  hipMemsetAsync(counts, 0, (size_t)N * sizeof(int), stream);

  k_transpose_w<<<(K_IN * O_OUT) / 256, 256, 0, stream>>>(W, Wt);
  k_gemm_relu<<<(N + 63) / 64, 256, 0, stream>>>(x, Wt, b, h, N);
  k_hist<<<(E + 255) / 256, 256, 0, stream>>>(edst, counts, E);
  k_scan<<<1, 1024, 0, stream>>>(counts, offsets, N);
  hipMemcpyAsync(cursor, offsets, (size_t)N * sizeof(int),
                 hipMemcpyDeviceToDevice, stream);
  k_scatter<<<(E + 255) / 256, 256, 0, stream>>>(esrc, edst, cursor, bucket, E);
  k_agg<<<(N + 3) / 4, 256, 0, stream>>>(offsets, bucket, h, out, N);
}